// Round 10
// baseline (135.464 us; speedup 1.0000x reference)
//
#include <hip/hip_runtime.h>
#include <hip/hip_bf16.h>
#include <hip/hip_cooperative_groups.h>

namespace cg = cooperative_groups;

typedef __attribute__((ext_vector_type(8))) short short8;
typedef __attribute__((ext_vector_type(4))) float floatx4;

#define B_ROWS 8192
#define DIM 128
#define NPAIR 4095
// rows scaled by sqrt(log2(e)) so S_mfma = S * log2(e) and exp(S) = exp2(S_mfma)
#define RSCALE 1.2011224087864498f
#define LN2F 0.6931471805599453f

#define GLOAD_LDS16(gp, lp)                                                     \
    __builtin_amdgcn_global_load_lds(                                           \
        (const __attribute__((address_space(1))) void*)(gp),                    \
        (__attribute__((address_space(3))) void*)(lp), 16, 0, 0)

// ---- stage one 64x128 bf16 half-slab to LDS (linear dest, pre-swizzled source) ----
__device__ __forceinline__ void stage_half(const __hip_bfloat16* __restrict__ gsrc,
                                           __hip_bfloat16* lbuf, int tid) {
    const int wid = tid >> 6;
    const int lane = tid & 63;
    #pragma unroll
    for (int it = 0; it < 4; ++it) {
        const int woff = it * 2048 + wid * 512;  // wave-uniform elem offset
        const int e = woff + lane * 8;
        const int src = (e & ~127) | ((e & 127) ^ (((e >> 7) & 7) << 3));
        GLOAD_LDS16(gsrc + src, lbuf + woff);
    }
}

// =================== fused single cooperative kernel ===================
// grid (8, 64) = 512 blocks (2/CU co-resident), 256 threads, 48KB LDS.
// Phase 1: normalize rows -> bf16 XN (scaled by sqrt(log2e)); zero out.
// Phase 2: r8 GEMM core (A in regs, B 3-buffer counted-vmcnt LDS pipeline),
//          exp row-sums into P[16][8192]; pair similarities extracted from
//          the diagonal tile's accumulator (S = acc * ln2).
// Phase 3: Z[r] = sum_slots, loss = (sum logZ - 2 sum pair) / B via atomicAdd.
__global__ void __launch_bounds__(256, 2) kfused(const float* __restrict__ X,
                                                 __hip_bfloat16* __restrict__ XN,
                                                 float* __restrict__ P,
                                                 float* __restrict__ pairT,
                                                 float* __restrict__ out) {
    __shared__ __hip_bfloat16 Bs[3][64 * DIM];

    const int tid = threadIdx.x;
    const int wid = tid >> 6;
    const int lane = tid & 63;
    const int lr = lane & 15;
    const int lk = lane >> 4;
    const int wr = wid >> 1;
    const int wc = wid & 1;
    const int g = blockIdx.x;   // col group 0..7
    const int rb = blockIdx.y;  // row panel 0..63
    const int bidl = rb * 8 + g;

    // ---------------- phase 1: normalize 16 rows ----------------
    #pragma unroll
    for (int rr = 0; rr < 4; ++rr) {
        const int row = bidl * 16 + wid * 4 + rr;
        const float2 v = *reinterpret_cast<const float2*>(X + row * DIM + lane * 2);
        float ss = v.x * v.x + v.y * v.y;
        #pragma unroll
        for (int m = 1; m < 64; m <<= 1) ss += __shfl_xor(ss, m, 64);
        const float rn = (ss > 0.f ? rsqrtf(ss) : 0.f) * RSCALE;
        *reinterpret_cast<__hip_bfloat162*>(XN + row * DIM + lane * 2) =
            __float22bfloat162_rn(make_float2(v.x * rn, v.y * rn));
    }
    if (bidl == 0 && tid == 0) out[0] = 0.f;

    cg::this_grid().sync();

    // ---------------- phase 2: GEMM + exp row sums ----------------
    {
        // A: 64 rows in registers: a[kk][m], rows rb*128 + wr*64 + m*16 + lr
        short8 a[4][4];
        const __hip_bfloat16* Abase = XN + (rb * 128 + wr * 64 + lr) * DIM + lk * 8;
        #pragma unroll
        for (int m = 0; m < 4; ++m)
            #pragma unroll
            for (int kk = 0; kk < 4; ++kk)
                a[kk][m] = *reinterpret_cast<const short8*>(Abase + m * 16 * DIM + kk * 32);

        float rp[4][4];
        #pragma unroll
        for (int m = 0; m < 4; ++m)
            #pragma unroll
            for (int r = 0; r < 4; ++r) rp[m][r] = 0.f;

        const floatx4 zero4 = {0.f, 0.f, 0.f, 0.f};

        // prologue: stage slabs 0 and 1 (slab s = tile g*8 + (s>>1), half s&1)
        stage_half(XN + (size_t)(g * 8) * 128 * DIM, Bs[0], tid);
        stage_half(XN + ((size_t)(g * 8) * 128 + 64) * DIM, Bs[1], tid);

        for (int t = 0; t < 16; ++t) {
            if (t < 15)
                asm volatile("s_waitcnt vmcnt(4)" ::: "memory");
            else
                asm volatile("s_waitcnt vmcnt(0)" ::: "memory");
            __builtin_amdgcn_s_barrier();  // raw barrier: no vmcnt drain

            if (t + 2 < 16)
                stage_half(XN + ((size_t)(g * 8 + ((t + 2) >> 1)) * 128 + ((t + 2) & 1) * 64) * DIM,
                           Bs[(t + 2) % 3], tid);

            const __hip_bfloat16* Bt = Bs[t % 3];
            const int cbj = g * 8 + (t >> 1);
            const bool dzero = (cbj == rb) && ((t & 1) == wr);

            __builtin_amdgcn_s_setprio(1);
            short8 b[4][2];
            #pragma unroll
            for (int n = 0; n < 2; ++n) {
                const int row = wc * 32 + n * 16 + lr;
                #pragma unroll
                for (int kk = 0; kk < 4; ++kk) {
                    const int col = (kk * 32 + lk * 8) ^ ((row & 7) << 3);
                    b[kk][n] = *reinterpret_cast<const short8*>(&Bt[row * DIM + col]);
                }
            }

            floatx4 acc[4][2];
            #pragma unroll
            for (int m = 0; m < 4; ++m)
                #pragma unroll
                for (int n = 0; n < 2; ++n)
                    acc[m][n] = __builtin_amdgcn_mfma_f32_16x16x32_bf16(a[0][m], b[0][n], zero4, 0, 0, 0);
            #pragma unroll
            for (int kk = 1; kk < 4; ++kk)
                #pragma unroll
                for (int m = 0; m < 4; ++m)
                    #pragma unroll
                    for (int n = 0; n < 2; ++n)
                        acc[m][n] = __builtin_amdgcn_mfma_f32_16x16x32_bf16(a[kk][m], b[kk][n], acc[m][n], 0, 0, 0);
            __builtin_amdgcn_s_setprio(0);

            if (dzero) {
                #pragma unroll
                for (int m = 0; m < 4; ++m)
                    #pragma unroll
                    for (int n = 0; n < 2; ++n)
                        #pragma unroll
                        for (int r = 0; r < 4; ++r) {
                            const int Rl = m * 16 + lk * 4 + r;   // local row 0..63
                            const int Cl = wc * 32 + n * 16 + lr; // local col 0..63
                            const float av = acc[m][n][r];
                            float e = __builtin_amdgcn_exp2f(av);
                            if (Rl == Cl) e = 0.f;
                            rp[m][r] += e;
                            // pair similarity S[2p, 2p+1]: col == row+1, row even
                            if (Cl == Rl + 1 && (Rl & 1) == 0) {
                                const int Rg = rb * 128 + wr * 64 + Rl;
                                if (Rg < B_ROWS - 2) pairT[Rg >> 1] = av * LN2F;
                            }
                        }
            } else {
                #pragma unroll
                for (int m = 0; m < 4; ++m)
                    #pragma unroll
                    for (int n = 0; n < 2; ++n)
                        #pragma unroll
                        for (int r = 0; r < 4; ++r)
                            rp[m][r] += __builtin_amdgcn_exp2f(acc[m][n][r]);
            }
        }

        // row sums: reduce over lr, store slot (g*2 + wc)
        #pragma unroll
        for (int m = 0; m < 4; ++m)
            #pragma unroll
            for (int r = 0; r < 4; ++r) {
                float v = rp[m][r];
                v += __shfl_xor(v, 1, 64);
                v += __shfl_xor(v, 2, 64);
                v += __shfl_xor(v, 4, 64);
                v += __shfl_xor(v, 8, 64);
                if (lr == 0) {
                    const int row = rb * 128 + wr * 64 + m * 16 + lk * 4 + r;
                    P[(g * 2 + wc) * B_ROWS + row] = v;
                }
            }
    }

    cg::this_grid().sync();

    // ---------------- phase 3: final reduction ----------------
    {
        float s = 0.f;
        if (tid < 16) {
            const int r = bidl * 16 + tid;
            if (r < B_ROWS - 2) {
                float z = 0.f;
                #pragma unroll
                for (int t = 0; t < 16; ++t) z += P[t * B_ROWS + r];
                s = logf(z);
            }
        } else if (tid < 24) {
            const int p = bidl * 8 + (tid - 16);
            if (p < NPAIR) s = -2.f * pairT[p];
        }
        #pragma unroll
        for (int m = 1; m < 64; m <<= 1) s += __shfl_xor(s, m, 64);
        float* red = (float*)&Bs[0][0];
        __syncthreads();
        if (lane == 0) red[wid] = s;
        __syncthreads();
        if (tid == 0)
            atomicAdd(out, (red[0] + red[1] + red[2] + red[3]) / (float)B_ROWS);
    }
}

// =================== fallback 3-kernel path (r8) ===================
__global__ void kprep(const float* __restrict__ X, __hip_bfloat16* __restrict__ XN,
                      float* __restrict__ pairT, float* __restrict__ out) {
    __shared__ float2 lds[4][64];
    const int wid = threadIdx.x >> 6;
    const int lane = threadIdx.x & 63;
    const int row = blockIdx.x * 4 + wid;

    const float2 v = *reinterpret_cast<const float2*>(X + row * DIM + lane * 2);
    float ss = v.x * v.x + v.y * v.y;
    #pragma unroll
    for (int m = 1; m < 64; m <<= 1) ss += __shfl_xor(ss, m, 64);
    const float rn = ss > 0.f ? rsqrtf(ss) : 0.f;
    const float2 nv = make_float2(v.x * rn, v.y * rn);

    *reinterpret_cast<__hip_bfloat162*>(XN + row * DIM + lane * 2) =
        __float22bfloat162_rn(make_float2(nv.x * RSCALE, nv.y * RSCALE));
    lds[wid][lane] = nv;
    __syncthreads();

    if ((wid & 1) == 0) {
        const int p = blockIdx.x * 2 + (wid >> 1);
        if (p < NPAIR) {
            const float2 a = lds[wid][lane];
            const float2 b = lds[wid + 1][lane];
            float d = a.x * b.x + a.y * b.y;
            #pragma unroll
            for (int m = 1; m < 64; m <<= 1) d += __shfl_xor(d, m, 64);
            if (lane == 0) pairT[p] = d;
        }
    }
    if (blockIdx.x == 0 && threadIdx.x == 0) out[0] = 0.f;
}

__global__ void __launch_bounds__(256, 2) kgemm(const __hip_bfloat16* __restrict__ XN,
                                                float* __restrict__ ZP) {
    __shared__ __hip_bfloat16 Bs[3][64 * DIM];

    const int tid = threadIdx.x;
    const int wid = tid >> 6;
    const int lane = tid & 63;
    const int lr = lane & 15;
    const int lk = lane >> 4;
    const int wr = wid >> 1;
    const int wc = wid & 1;
    const int rb = blockIdx.y;
    const int g = blockIdx.x;

    short8 a[4][4];
    const __hip_bfloat16* Abase = XN + (rb * 128 + wr * 64 + lr) * DIM + lk * 8;
    #pragma unroll
    for (int m = 0; m < 4; ++m)
        #pragma unroll
        for (int kk = 0; kk < 4; ++kk)
            a[kk][m] = *reinterpret_cast<const short8*>(Abase + m * 16 * DIM + kk * 32);

    float rp[4][4];
    #pragma unroll
    for (int m = 0; m < 4; ++m)
        #pragma unroll
        for (int r = 0; r < 4; ++r) rp[m][r] = 0.f;

    const floatx4 zero4 = {0.f, 0.f, 0.f, 0.f};

    stage_half(XN + (size_t)(g * 8) * 128 * DIM, Bs[0], tid);
    stage_half(XN + ((size_t)(g * 8) * 128 + 64) * DIM, Bs[1], tid);

    for (int t = 0; t < 16; ++t) {
        if (t < 15)
            asm volatile("s_waitcnt vmcnt(4)" ::: "memory");
        else
            asm volatile("s_waitcnt vmcnt(0)" ::: "memory");
        __builtin_amdgcn_s_barrier();

        if (t + 2 < 16)
            stage_half(XN + ((size_t)(g * 8 + ((t + 2) >> 1)) * 128 + ((t + 2) & 1) * 64) * DIM,
                       Bs[(t + 2) % 3], tid);

        const __hip_bfloat16* Bt = Bs[t % 3];
        const int cbj = g * 8 + (t >> 1);
        const bool dzero = (cbj == rb) && ((t & 1) == wr);

        __builtin_amdgcn_s_setprio(1);
        short8 b[4][2];
        #pragma unroll
        for (int n = 0; n < 2; ++n) {
            const int row = wc * 32 + n * 16 + lr;
            #pragma unroll
            for (int kk = 0; kk < 4; ++kk) {
                const int col = (kk * 32 + lk * 8) ^ ((row & 7) << 3);
                b[kk][n] = *reinterpret_cast<const short8*>(&Bt[row * DIM + col]);
            }
        }

        floatx4 acc[4][2];
        #pragma unroll
        for (int m = 0; m < 4; ++m)
            #pragma unroll
            for (int n = 0; n < 2; ++n)
                acc[m][n] = __builtin_amdgcn_mfma_f32_16x16x32_bf16(a[0][m], b[0][n], zero4, 0, 0, 0);
        #pragma unroll
        for (int kk = 1; kk < 4; ++kk)
            #pragma unroll
            for (int m = 0; m < 4; ++m)
                #pragma unroll
                for (int n = 0; n < 2; ++n)
                    acc[m][n] = __builtin_amdgcn_mfma_f32_16x16x32_bf16(a[kk][m], b[kk][n], acc[m][n], 0, 0, 0);
        __builtin_amdgcn_s_setprio(0);

        if (dzero) {
            #pragma unroll
            for (int m = 0; m < 4; ++m)
                #pragma unroll
                for (int n = 0; n < 2; ++n)
                    #pragma unroll
                    for (int r = 0; r < 4; ++r) {
                        float e = __builtin_amdgcn_exp2f(acc[m][n][r]);
                        if (m * 16 + lk * 4 + r == wc * 32 + n * 16 + lr) e = 0.f;
                        rp[m][r] += e;
                    }
        } else {
            #pragma unroll
            for (int m = 0; m < 4; ++m)
                #pragma unroll
                for (int n = 0; n < 2; ++n)
                    #pragma unroll
                    for (int r = 0; r < 4; ++r)
                        rp[m][r] += __builtin_amdgcn_exp2f(acc[m][n][r]);
        }
    }

    #pragma unroll
    for (int m = 0; m < 4; ++m)
        #pragma unroll
        for (int r = 0; r < 4; ++r) {
            float v = rp[m][r];
            v += __shfl_xor(v, 1, 64);
            v += __shfl_xor(v, 2, 64);
            v += __shfl_xor(v, 4, 64);
            v += __shfl_xor(v, 8, 64);
            if (lr == 0) {
                const int row = rb * 128 + wr * 64 + m * 16 + lk * 4 + r;
                P_STORE:
                ZP[(g * 2 + wc) * B_ROWS + row] = v;
            }
        }
}

__global__ void kfinalP(const float* __restrict__ P, const float* __restrict__ pairT,
                        float* __restrict__ out) {
    const int r = blockIdx.x * 256 + threadIdx.x;
    float s = 0.f;
    if (r < B_ROWS - 2) {
        float z = 0.f;
        #pragma unroll
        for (int tt = 0; tt < 16; ++tt) z += P[tt * B_ROWS + r];
        s = logf(z);
    }
    if (r < NPAIR) s -= 2.f * pairT[r];
    #pragma unroll
    for (int m = 1; m < 64; m <<= 1) s += __shfl_xor(s, m, 64);
    __shared__ float red[4];
    const int wid = threadIdx.x >> 6;
    const int lane = threadIdx.x & 63;
    if (lane == 0) red[wid] = s;
    __syncthreads();
    if (threadIdx.x == 0) {
        float tsum = red[0] + red[1] + red[2] + red[3];
        atomicAdd(out, tsum / (float)B_ROWS);
    }
}

extern "C" void kernel_launch(void* const* d_in, const int* in_sizes, int n_in,
                              void* d_out, int out_size, void* d_ws, size_t ws_size,
                              hipStream_t stream) {
    (void)in_sizes; (void)n_in; (void)out_size; (void)ws_size;
    const float* X = (const float*)d_in[0];
    float* out = (float*)d_out;
    char* ws = (char*)d_ws;

    float* pairT = (float*)ws;                               // 16 KB
    __hip_bfloat16* XN = (__hip_bfloat16*)(ws + 32768);      // 2 MB
    float* P = (float*)(ws + 32768 + 2097152);               // 512 KB (16 x 8192 f32)

    void* args[] = {(void*)&X, (void*)&XN, (void*)&P, (void*)&pairT, (void*)&out};
    hipError_t e = hipLaunchCooperativeKernel((const void*)kfused, dim3(8, 64),
                                              dim3(256), args, 0, stream);
    if (e != hipSuccess) {
        // fallback: 3-kernel path (r8)
        kprep<<<2048, 256, 0, stream>>>(X, XN, pairT, out);
        kgemm<<<dim3(8, 64), 256, 0, stream>>>(XN, P);
        kfinalP<<<32, 256, 0, stream>>>(P, pairT, out);
    }
}

// Round 11
// 44.667 us; speedup vs baseline: 3.0327x; 3.0327x over previous
//
#include <hip/hip_runtime.h>
#include <hip/hip_bf16.h>

typedef __attribute__((ext_vector_type(8))) short short8;
typedef __attribute__((ext_vector_type(4))) float floatx4;

#define B_ROWS 8192
#define DIM 128
#define NPAIR 4095
#define NSLOT 32
// rows scaled by sqrt(log2(e)) so S_mfma = S * log2(e) and exp(S) = exp2(S_mfma)
#define RSCALE 1.2011224087864498f

#define GLOAD_LDS16(gp, lp)                                                     \
    __builtin_amdgcn_global_load_lds(                                           \
        (const __attribute__((address_space(1))) void*)(gp),                    \
        (__attribute__((address_space(3))) void*)(lp), 16, 0, 0)

// ---------------- zero Z (fallback path only) ----------------
__global__ void kzero(float* __restrict__ Z) {
    int i = blockIdx.x * 256 + threadIdx.x;
    if (i < B_ROWS) Z[i] = 0.f;
}

// ------------- fused prep: normalize rows -> bf16 (scaled), pair dots, zero out -------------
__global__ void kprep(const float* __restrict__ X, __hip_bfloat16* __restrict__ XN,
                      float* __restrict__ pairT, float* __restrict__ out) {
    __shared__ float2 lds[4][64];
    const int wid = threadIdx.x >> 6;
    const int lane = threadIdx.x & 63;
    const int row = blockIdx.x * 4 + wid;

    const float2 v = *reinterpret_cast<const float2*>(X + row * DIM + lane * 2);
    float ss = v.x * v.x + v.y * v.y;
    #pragma unroll
    for (int m = 1; m < 64; m <<= 1) ss += __shfl_xor(ss, m, 64);
    const float rn = ss > 0.f ? rsqrtf(ss) : 0.f;
    const float2 nv = make_float2(v.x * rn, v.y * rn);

    *reinterpret_cast<__hip_bfloat162*>(XN + row * DIM + lane * 2) =
        __float22bfloat162_rn(make_float2(nv.x * RSCALE, nv.y * RSCALE));
    lds[wid][lane] = nv;  // unscaled for exact pair dot
    __syncthreads();

    if ((wid & 1) == 0) {
        const int p = blockIdx.x * 2 + (wid >> 1);
        if (p < NPAIR) {
            const float2 a = lds[wid][lane];
            const float2 b = lds[wid + 1][lane];
            float d = a.x * b.x + a.y * b.y;
            #pragma unroll
            for (int m = 1; m < 64; m <<= 1) d += __shfl_xor(d, m, 64);
            if (lane == 0) pairT[p] = d;
        }
    }
    if (blockIdx.x == 0 && threadIdx.x == 0) out[0] = 0.f;
}

// ---- stage one 32x128 bf16 slab (8KB) to LDS, 128-thread block ----
// LDS[row][colL] = global[row][colL ^ ((row&7)<<3)] (pre-swizzled source)
__device__ __forceinline__ void stage32(const __hip_bfloat16* __restrict__ gsrc,
                                        __hip_bfloat16* lbuf, int tid) {
    const int wid = tid >> 6;   // 0..1
    const int lane = tid & 63;
    #pragma unroll
    for (int it = 0; it < 4; ++it) {
        const int woff = it * 1024 + wid * 512;  // wave-uniform elem offset
        const int e = woff + lane * 8;
        const int src = (e & ~127) | ((e & 127) ^ (((e >> 7) & 7) << 3));
        GLOAD_LDS16(gsrc + src, lbuf + woff);
    }
}

// ------------- main: small-block high-occupancy GEMM -------------
// grid (32, 64): y = row panel rb (128 rows), x = col group g (256 cols = 8 slabs).
// Block = 128 threads = 2 waves; wave w owns rows rb*128 + w*64 (A in regs);
// both waves share the 32-col B slab. 2-buffer LDS (16KB), simple drain/phase.
// ~5-6 blocks/CU co-resident: cross-block overlap hides stage/drain stalls.
template <bool USEP>
__global__ void __launch_bounds__(128) kgemm(const __hip_bfloat16* __restrict__ XN,
                                             float* __restrict__ ZP) {
    __shared__ __hip_bfloat16 Bs[2][32 * DIM];

    const int tid = threadIdx.x;
    const int w = tid >> 6;     // wave 0..1
    const int lane = tid & 63;
    const int lr = lane & 15;
    const int lk = lane >> 4;
    const int rb = blockIdx.y;
    const int g = blockIdx.x;

    // ---- A: 64 rows in registers: a[kk][m], rows rb*128 + w*64 + m*16 + lr ----
    short8 a[4][4];
    const __hip_bfloat16* Abase = XN + (rb * 128 + w * 64 + lr) * DIM + lk * 8;
    #pragma unroll
    for (int m = 0; m < 4; ++m)
        #pragma unroll
        for (int kk = 0; kk < 4; ++kk)
            a[kk][m] = *reinterpret_cast<const short8*>(Abase + m * 16 * DIM + kk * 32);

    float rp[4][4];
    #pragma unroll
    for (int m = 0; m < 4; ++m)
        #pragma unroll
        for (int r = 0; r < 4; ++r) rp[m][r] = 0.f;

    const floatx4 zero4 = {0.f, 0.f, 0.f, 0.f};
    const int R0 = rb * 2 + w;  // wave's 64-row block index

    // prologue: stage slab 0
    stage32(XN + (size_t)(g * 256) * DIM, Bs[0], tid);
    __syncthreads();

    for (int s = 0; s < 8; ++s) {
        const int cur = s & 1;
        // issue next-slab DMA first: overlaps this phase's ds_read + MFMA + exp
        if (s < 7)
            stage32(XN + (size_t)(g * 256 + (s + 1) * 32) * DIM, Bs[cur ^ 1], tid);

        const __hip_bfloat16* Bt = Bs[cur];
        const int C0 = g * 256 + s * 32;           // slab's global col base
        const bool dzero = ((C0 >> 6) == R0);      // slab within wave's diag block
        const int coff = C0 & 32;                  // 0 or 32 within the 64-block

        __builtin_amdgcn_s_setprio(1);
        // B fragments: slab-local cols n*16 + lr, swizzled read
        short8 b[4][2];
        #pragma unroll
        for (int n = 0; n < 2; ++n) {
            const int row = n * 16 + lr;
            #pragma unroll
            for (int kk = 0; kk < 4; ++kk) {
                const int col = (kk * 32 + lk * 8) ^ ((row & 7) << 3);
                b[kk][n] = *reinterpret_cast<const short8*>(&Bt[row * DIM + col]);
            }
        }

        floatx4 acc[4][2];
        #pragma unroll
        for (int m = 0; m < 4; ++m)
            #pragma unroll
            for (int n = 0; n < 2; ++n)
                acc[m][n] = __builtin_amdgcn_mfma_f32_16x16x32_bf16(a[0][m], b[0][n], zero4, 0, 0, 0);
        #pragma unroll
        for (int kk = 1; kk < 4; ++kk)
            #pragma unroll
            for (int m = 0; m < 4; ++m)
                #pragma unroll
                for (int n = 0; n < 2; ++n)
                    acc[m][n] = __builtin_amdgcn_mfma_f32_16x16x32_bf16(a[kk][m], b[kk][n], acc[m][n], 0, 0, 0);
        __builtin_amdgcn_s_setprio(0);

        if (dzero) {
            #pragma unroll
            for (int m = 0; m < 4; ++m)
                #pragma unroll
                for (int n = 0; n < 2; ++n)
                    #pragma unroll
                    for (int r = 0; r < 4; ++r) {
                        float e = __builtin_amdgcn_exp2f(acc[m][n][r]);
                        if (m * 16 + lk * 4 + r == coff + n * 16 + lr) e = 0.f;
                        rp[m][r] += e;
                    }
        } else {
            #pragma unroll
            for (int m = 0; m < 4; ++m)
                #pragma unroll
                for (int n = 0; n < 2; ++n)
                    #pragma unroll
                    for (int r = 0; r < 4; ++r)
                        rp[m][r] += __builtin_amdgcn_exp2f(acc[m][n][r]);
        }
        // drain barrier: next slab's DMA completes; buffer reuse ordered.
        // cross-block overlap (5-6 blocks/CU) hides the drain.
        __syncthreads();
    }

    // ---- row sums: reduce over lr, store slot g ----
    #pragma unroll
    for (int m = 0; m < 4; ++m)
        #pragma unroll
        for (int r = 0; r < 4; ++r) {
            float v = rp[m][r];
            v += __shfl_xor(v, 1, 64);
            v += __shfl_xor(v, 2, 64);
            v += __shfl_xor(v, 4, 64);
            v += __shfl_xor(v, 8, 64);
            if (lr == 0) {
                const int row = rb * 128 + w * 64 + m * 16 + lk * 4 + r;
                if (USEP)
                    ZP[g * B_ROWS + row] = v;
                else
                    atomicAdd(&ZP[row], v);
            }
        }
}

// ------------- final (P path): Z[r] = sum_{32 slots} P[t][r]; loss reduce -------------
__global__ void kfinalP(const float* __restrict__ P, const float* __restrict__ pairT,
                        float* __restrict__ out) {
    const int r = blockIdx.x * 256 + threadIdx.x;
    float s = 0.f;
    if (r < B_ROWS - 2) {
        float z = 0.f;
        #pragma unroll
        for (int tt = 0; tt < NSLOT; ++tt) z += P[tt * B_ROWS + r];
        s = logf(z);
    }
    if (r < NPAIR) s -= 2.f * pairT[r];
    #pragma unroll
    for (int m = 1; m < 64; m <<= 1) s += __shfl_xor(s, m, 64);
    __shared__ float red[4];
    const int wid = threadIdx.x >> 6;
    const int lane = threadIdx.x & 63;
    if (lane == 0) red[wid] = s;
    __syncthreads();
    if (threadIdx.x == 0) {
        float tsum = red[0] + red[1] + red[2] + red[3];
        atomicAdd(out, tsum / (float)B_ROWS);
    }
}

// ------------- final (Z fallback path) -------------
__global__ void kfinalZ(const float* __restrict__ Z, const float* __restrict__ pairT,
                        float* __restrict__ out) {
    float s = 0.f;
    for (int r = threadIdx.x; r < B_ROWS - 2; r += 1024) s += logf(Z[r]);
    for (int p = threadIdx.x; p < NPAIR; p += 1024) s -= 2.f * pairT[p];
    #pragma unroll
    for (int m = 1; m < 64; m <<= 1) s += __shfl_xor(s, m, 64);
    __shared__ float red[16];
    const int wid = threadIdx.x >> 6;
    const int lane = threadIdx.x & 63;
    if (lane == 0) red[wid] = s;
    __syncthreads();
    if (threadIdx.x == 0) {
        float t = 0.f;
        #pragma unroll
        for (int i = 0; i < 16; ++i) t += red[i];
        out[0] = t / (float)B_ROWS;
    }
}

extern "C" void kernel_launch(void* const* d_in, const int* in_sizes, int n_in,
                              void* d_out, int out_size, void* d_ws, size_t ws_size,
                              hipStream_t stream) {
    (void)in_sizes; (void)n_in; (void)out_size;
    const float* X = (const float*)d_in[0];
    float* out = (float*)d_out;
    char* ws = (char*)d_ws;

    float* Z = (float*)ws;                                   // 32 KB
    float* pairT = (float*)(ws + 32768);                     // 16 KB
    __hip_bfloat16* XN = (__hip_bfloat16*)(ws + 49152);      // 2 MB
    float* P = (float*)(ws + 49152 + 2097152);               // 1 MB (32 x 8192 f32)
    const size_t need = 49152 + 2097152 + (size_t)NSLOT * B_ROWS * 4;
    const bool useP = ws_size >= need;

    kprep<<<2048, 256, 0, stream>>>(X, XN, pairT, out);
    if (useP) {
        kgemm<true><<<dim3(32, 64), 128, 0, stream>>>(XN, P);
        kfinalP<<<32, 256, 0, stream>>>(P, pairT, out);
    } else {
        kzero<<<32, 256, 0, stream>>>(Z);
        kgemm<false><<<dim3(32, 64), 128, 0, stream>>>(XN, Z);
        kfinalZ<<<1, 1024, 0, stream>>>(Z, pairT, out);
    }
}